// Round 1
// baseline (345.763 us; speedup 1.0000x reference)
//
#include <hip/hip_runtime.h>
#include <stdint.h>

#define NBATCH 32

// ws layout: header only (~640 B)
struct WsHdr {
  unsigned long long keysel[NBATCH]; // selected 56-bit k-th smallest key per segment
  int counts[NBATCH];
  int starts[NBATCH];
  int ndrop[NBATCH];
};

// monotone float->uint transform (scores are in [0,1) but be robust)
__device__ __forceinline__ unsigned int ordbits(float s) {
  unsigned int u = __float_as_uint(s);
  return (u & 0x80000000u) ? ~u : (u | 0x80000000u);
}

__global__ void k_zero(WsHdr* ws) {
  int t = threadIdx.x;
  if (t < NBATCH) ws->counts[t] = 0;
}

__global__ void k_hist(const int* __restrict__ batch, int n, WsHdr* ws) {
  __shared__ int h[NBATCH];
  if (threadIdx.x < NBATCH) h[threadIdx.x] = 0;
  __syncthreads();
  int stride = gridDim.x * blockDim.x;
  for (int i = blockIdx.x * blockDim.x + threadIdx.x; i < n; i += stride)
    atomicAdd(&h[batch[i]], 1);
  __syncthreads();
  if (threadIdx.x < NBATCH) atomicAdd(&ws->counts[threadIdx.x], h[threadIdx.x]);
}

__global__ void k_scan(WsHdr* ws) {
  if (threadIdx.x == 0) {
    int acc = 0;
    for (int b = 0; b < NBATCH; ++b) {
      int c = ws->counts[b];
      ws->starts[b] = acc;
      ws->ndrop[b] = c >> 1;   // floor(c * 0.5) exact
      acc += c;
    }
  }
}

// one block per segment; 8-bit radix select of k-th smallest 56-bit key
__global__ void k_select(const float* __restrict__ scores, WsHdr* ws) {
  __shared__ unsigned int hist[256];
  __shared__ unsigned long long sh_prefix;
  __shared__ int sh_krem;
  int b = blockIdx.x;
  int start = ws->starts[b];
  int cnt = ws->counts[b];
  if (threadIdx.x == 0) { sh_prefix = 0ull; sh_krem = ws->ndrop[b]; }
  __syncthreads();
  for (int shift = 48; shift >= 0; shift -= 8) {
    for (int j = threadIdx.x; j < 256; j += blockDim.x) hist[j] = 0;
    __syncthreads();
    unsigned long long prefix = sh_prefix;
    for (int idx = threadIdx.x; idx < cnt; idx += blockDim.x) {
      unsigned long long key =
          ((unsigned long long)ordbits(scores[start + idx]) << 24) | (unsigned int)idx;
      if ((key >> (shift + 8)) == prefix)
        atomicAdd(&hist[(unsigned int)(key >> shift) & 255u], 1u);
    }
    __syncthreads();
    if (threadIdx.x == 0) {
      int krem = sh_krem;
      unsigned int cum = 0;
      unsigned int sel = 255;
      for (int j = 0; j < 256; ++j) {
        unsigned int c = hist[j];
        if ((unsigned int)krem < cum + c) { sel = (unsigned int)j; krem -= (int)cum; break; }
        cum += c;
      }
      sh_prefix = (prefix << 8) | sel;
      sh_krem = krem;
    }
    __syncthreads();
  }
  if (threadIdx.x == 0) ws->keysel[b] = sh_prefix;
}

// 16 float4 chunks per row (C=64); 16 points per 256-thread block
__global__ void k_apply(const float4* __restrict__ feats4,
                        const int* __restrict__ batch,
                        const float* __restrict__ scores,
                        const WsHdr* __restrict__ ws,
                        float4* __restrict__ out4, int n) {
  __shared__ float m[16];
  int t = threadIdx.x;
  int pl = t >> 4, ch = t & 15;
  int i = blockIdx.x * 16 + pl;
  if (ch == 0) {
    float keep = 0.f;
    if (i < n) {
      int b = batch[i];
      int start = ws->starts[b];
      unsigned long long key =
          ((unsigned long long)ordbits(scores[i]) << 24) | (unsigned int)(i - start);
      keep = (key >= ws->keysel[b]) ? 1.f : 0.f;
    }
    m[pl] = keep;
  }
  __syncthreads();
  if (i < n) {
    size_t off = (size_t)i * 16 + (size_t)ch;
    float4 v = feats4[off];
    float s = m[pl];
    v.x *= s; v.y *= s; v.z *= s; v.w *= s;
    out4[off] = v;
  }
}

extern "C" void kernel_launch(void* const* d_in, const int* in_sizes, int n_in,
                              void* d_out, int out_size, void* d_ws, size_t ws_size,
                              hipStream_t stream) {
  const float* feats  = (const float*)d_in[0];
  const int*   batch  = (const int*)d_in[1];
  const float* scores = (const float*)d_in[2];
  float* out = (float*)d_out;
  int n = in_sizes[1];            // number of points (batch_idx length)
  WsHdr* ws = (WsHdr*)d_ws;

  k_zero<<<1, 64, 0, stream>>>(ws);
  k_hist<<<1024, 256, 0, stream>>>(batch, n, ws);
  k_scan<<<1, 64, 0, stream>>>(ws);
  k_select<<<NBATCH, 256, 0, stream>>>(scores, ws);

  int blocks = (n + 15) / 16;     // 16 rows per block, 16 float4 per row
  k_apply<<<blocks, 256, 0, stream>>>((const float4*)feats, batch, scores, ws,
                                      (float4*)out, n);
}

// Round 2
// 249.016 us; speedup vs baseline: 1.3885x; 1.3885x over previous
//
#include <hip/hip_runtime.h>
#include <stdint.h>

#define NBATCH 32
#define NBIN16 65536
#define CAP 4096

typedef unsigned long long u64;
typedef unsigned int u32;

struct WsHdr {
  u64 keysel[NBATCH];  // selected 56-bit k-th smallest key per segment
  int counts[NBATCH];
  int starts[NBATCH];
  int ndrop[NBATCH];
  int sel16[NBATCH];   // selected 16-bit bucket (0x10000 = none/empty segment)
  int krem2[NBATCH];   // residual rank within selected bucket
  int ccount[NBATCH];  // candidate counts
  int pad[NBATCH];
};
// ws layout: WsHdr | u32 hist16[NBATCH*NBIN16] (8MB) | u64 cand[NBATCH*CAP] (1MB)

// monotone float->uint transform
__device__ __forceinline__ u32 ordbits(float s) {
  u32 u = __float_as_uint(s);
  return (u & 0x80000000u) ? ~u : (u | 0x80000000u);
}

// ---------------- fast path ----------------

__global__ void k_hist16(const int* __restrict__ batch, const float* __restrict__ scores,
                         int n, u32* __restrict__ hist) {
  int stride = gridDim.x * blockDim.x;
  for (int i = blockIdx.x * blockDim.x + threadIdx.x; i < n; i += stride) {
    u32 t = ordbits(scores[i]) >> 16;
    atomicAdd(&hist[(size_t)batch[i] * NBIN16 + t], 1u);
  }
}

__global__ void k_counts(const u32* __restrict__ hist, WsHdr* ws) {
  __shared__ int red[256];
  int b = blockIdx.x, t = threadIdx.x;
  const u32* h = hist + (size_t)b * NBIN16;
  int s = 0;
  for (int j = t; j < NBIN16; j += 256) s += h[j];   // coalesced
  red[t] = s; __syncthreads();
  for (int off = 128; off > 0; off >>= 1) {
    if (t < off) red[t] += red[t + off];
    __syncthreads();
  }
  if (t == 0) ws->counts[b] = red[0];
}

__global__ void k_scan(WsHdr* ws) {
  if (threadIdx.x == 0) {
    int acc = 0;
    for (int b = 0; b < NBATCH; ++b) {
      int c = ws->counts[b];
      ws->starts[b] = acc;
      ws->ndrop[b] = c >> 1;   // floor(c * 0.5) exact
      acc += c;
    }
  }
}

// two-level parallel select of the bucket containing the k-th smallest key
__global__ void k_pick16(const u32* __restrict__ hist, WsHdr* ws) {
  __shared__ int sc[256];
  __shared__ int sh_w, sh_krem;
  int b = blockIdx.x, t = threadIdx.x;
  const u32* h = hist + (size_t)b * NBIN16;
  if (ws->counts[b] == 0) {
    if (t == 0) { ws->sel16[b] = 0x10000; ws->krem2[b] = 0; }
    return;
  }
  int krem = ws->ndrop[b];
  // level 1: stripe sums (stripe t = bins [t*256, t*256+256))
  int s = 0;
  for (int j = 0; j < 256; ++j) s += h[t * 256 + j];
  sc[t] = s; __syncthreads();
  for (int off = 1; off < 256; off <<= 1) {          // Hillis-Steele inclusive scan
    int v = (t >= off) ? sc[t - off] : 0;
    __syncthreads(); sc[t] += v; __syncthreads();
  }
  int excl = sc[t] - s;
  if (krem >= excl && krem < excl + s) { sh_w = t; sh_krem = krem - excl; }
  __syncthreads();
  int W = sh_w, krem1 = sh_krem;
  // level 2: the 256 bins of winning stripe, coalesced single read each
  int c = (int)h[W * 256 + t];
  sc[t] = c; __syncthreads();
  for (int off = 1; off < 256; off <<= 1) {
    int v = (t >= off) ? sc[t - off] : 0;
    __syncthreads(); sc[t] += v; __syncthreads();
  }
  int excl2 = sc[t] - c;
  if (krem1 >= excl2 && krem1 < excl2 + c) {
    ws->sel16[b] = W * 256 + t;
    ws->krem2[b] = krem1 - excl2;
  }
}

__global__ void k_compact(const int* __restrict__ batch, const float* __restrict__ scores,
                          int n, WsHdr* ws, u64* __restrict__ cand) {
  int stride = gridDim.x * blockDim.x;
  for (int i = blockIdx.x * blockDim.x + threadIdx.x; i < n; i += stride) {
    int b = batch[i];
    u32 ob = ordbits(scores[i]);
    if ((int)(ob >> 16) == ws->sel16[b]) {
      int p = atomicAdd(&ws->ccount[b], 1);
      if (p < CAP)
        cand[(size_t)b * CAP + p] = ((u64)ob << 24) | (u32)(i - ws->starts[b]);
    }
  }
}

__global__ void k_final(WsHdr* ws, const u64* __restrict__ cand) {
  __shared__ u64 ck[CAP];
  int b = blockIdx.x, t = threadIdx.x;
  int m = ws->ccount[b]; if (m > CAP) m = CAP;
  if (m == 0) { if (t == 0) ws->keysel[b] = 0ull; return; }
  for (int j = t; j < m; j += 256) ck[j] = cand[(size_t)b * CAP + j];
  __syncthreads();
  int krem = ws->krem2[b];
  for (int j = t; j < m; j += 256) {
    u64 key = ck[j];
    int r = 0;
    for (int q = 0; q < m; ++q) r += (ck[q] < key);  // broadcast LDS reads
    if (r == krem) ws->keysel[b] = key;
  }
}

// ---------------- fallback path (small ws): previous passing kernels ----------------

__global__ void k_zero(WsHdr* ws) {
  int t = threadIdx.x;
  if (t < NBATCH) ws->counts[t] = 0;
}

__global__ void k_hist(const int* __restrict__ batch, int n, WsHdr* ws) {
  __shared__ int h[NBATCH];
  if (threadIdx.x < NBATCH) h[threadIdx.x] = 0;
  __syncthreads();
  int stride = gridDim.x * blockDim.x;
  for (int i = blockIdx.x * blockDim.x + threadIdx.x; i < n; i += stride)
    atomicAdd(&h[batch[i]], 1);
  __syncthreads();
  if (threadIdx.x < NBATCH) atomicAdd(&ws->counts[threadIdx.x], h[threadIdx.x]);
}

__global__ void k_select(const float* __restrict__ scores, WsHdr* ws) {
  __shared__ u32 hist[256];
  __shared__ u64 sh_prefix;
  __shared__ int sh_krem;
  int b = blockIdx.x;
  int start = ws->starts[b];
  int cnt = ws->counts[b];
  if (threadIdx.x == 0) { sh_prefix = 0ull; sh_krem = ws->ndrop[b]; }
  __syncthreads();
  for (int shift = 48; shift >= 0; shift -= 8) {
    for (int j = threadIdx.x; j < 256; j += blockDim.x) hist[j] = 0;
    __syncthreads();
    u64 prefix = sh_prefix;
    for (int idx = threadIdx.x; idx < cnt; idx += blockDim.x) {
      u64 key = ((u64)ordbits(scores[start + idx]) << 24) | (u32)idx;
      if ((key >> (shift + 8)) == prefix)
        atomicAdd(&hist[(u32)(key >> shift) & 255u], 1u);
    }
    __syncthreads();
    if (threadIdx.x == 0) {
      int krem = sh_krem;
      u32 cum = 0, sel = 255;
      for (int j = 0; j < 256; ++j) {
        u32 c = hist[j];
        if ((u32)krem < cum + c) { sel = (u32)j; krem -= (int)cum; break; }
        cum += c;
      }
      sh_prefix = (prefix << 8) | sel;
      sh_krem = krem;
    }
    __syncthreads();
  }
  if (threadIdx.x == 0) ws->keysel[b] = sh_prefix;
}

// ---------------- apply (shared by both paths) ----------------

__global__ void k_apply(const float4* __restrict__ feats4,
                        const int* __restrict__ batch,
                        const float* __restrict__ scores,
                        const WsHdr* __restrict__ ws,
                        float4* __restrict__ out4, int n) {
  __shared__ float m[16];
  int t = threadIdx.x;
  int pl = t >> 4, ch = t & 15;
  int i = blockIdx.x * 16 + pl;
  if (ch == 0) {
    float keep = 0.f;
    if (i < n) {
      int b = batch[i];
      int start = ws->starts[b];
      u64 key = ((u64)ordbits(scores[i]) << 24) | (u32)(i - start);
      keep = (key >= ws->keysel[b]) ? 1.f : 0.f;
    }
    m[pl] = keep;
  }
  __syncthreads();
  if (i < n) {
    size_t off = (size_t)i * 16 + (size_t)ch;
    float4 v = feats4[off];
    float s = m[pl];
    v.x *= s; v.y *= s; v.z *= s; v.w *= s;
    out4[off] = v;
  }
}

extern "C" void kernel_launch(void* const* d_in, const int* in_sizes, int n_in,
                              void* d_out, int out_size, void* d_ws, size_t ws_size,
                              hipStream_t stream) {
  const float* feats  = (const float*)d_in[0];
  const int*   batch  = (const int*)d_in[1];
  const float* scores = (const float*)d_in[2];
  float* out = (float*)d_out;
  int n = in_sizes[1];
  WsHdr* ws = (WsHdr*)d_ws;

  const size_t hist_bytes = (size_t)NBATCH * NBIN16 * sizeof(u32);   // 8 MB
  const size_t cand_bytes = (size_t)NBATCH * CAP * sizeof(u64);      // 1 MB
  const size_t need = sizeof(WsHdr) + hist_bytes + cand_bytes;

  if (ws_size >= need) {
    u32* hist = (u32*)((char*)d_ws + sizeof(WsHdr));
    u64* cand = (u64*)((char*)d_ws + sizeof(WsHdr) + hist_bytes);
    hipMemsetAsync(d_ws, 0, sizeof(WsHdr) + hist_bytes, stream);
    k_hist16 <<<2048, 256, 0, stream>>>(batch, scores, n, hist);
    k_counts <<<NBATCH, 256, 0, stream>>>(hist, ws);
    k_scan   <<<1, 64, 0, stream>>>(ws);
    k_pick16 <<<NBATCH, 256, 0, stream>>>(hist, ws);
    k_compact<<<2048, 256, 0, stream>>>(batch, scores, n, ws, cand);
    k_final  <<<NBATCH, 256, 0, stream>>>(ws, cand);
  } else {
    k_zero  <<<1, 64, 0, stream>>>(ws);
    k_hist  <<<1024, 256, 0, stream>>>(batch, n, ws);
    k_scan  <<<1, 64, 0, stream>>>(ws);
    k_select<<<NBATCH, 256, 0, stream>>>(scores, ws);
  }

  int blocks = (n + 15) / 16;   // 16 rows per block, 16 float4 per row
  k_apply<<<blocks, 256, 0, stream>>>((const float4*)feats, batch, scores, ws,
                                      (float4*)out, n);
}

// Round 3
// 212.698 us; speedup vs baseline: 1.6256x; 1.1707x over previous
//
#include <hip/hip_runtime.h>
#include <stdint.h>

#define NBATCH 32
#define NBIN16 65536
#define CAP 4096

typedef unsigned long long u64;
typedef unsigned int u32;

struct WsHdr {
  u64 keysel[NBATCH];  // selected 56-bit k-th smallest key per segment
  int counts[NBATCH];
  int starts[NBATCH];
  int ndrop[NBATCH];
  int sel16[NBATCH];   // selected 16-bit bucket (0x10000 = none/empty segment)
  int krem2[NBATCH];   // residual rank within selected bucket
  int ccount[NBATCH];  // candidate counts
  int pad[NBATCH];
};
// ws layout: WsHdr | u32 hist16[NBATCH*NBIN16] (8MB) | u64 cand[NBATCH*CAP] (1MB)

// monotone float->uint transform
__device__ __forceinline__ u32 ordbits(float s) {
  u32 u = __float_as_uint(s);
  return (u & 0x80000000u) ? ~u : (u | 0x80000000u);
}

// ---------------- fast path ----------------

// zero header + hist16 with full write bandwidth (replaces 150us rocclr fill)
__global__ void k_zero_all(float4* __restrict__ p, int n16) {
  int stride = gridDim.x * blockDim.x;
  for (int i = blockIdx.x * blockDim.x + threadIdx.x; i < n16; i += stride)
    p[i] = make_float4(0.f, 0.f, 0.f, 0.f);
}

// 16-bit bucket histogram per segment + per-segment counts in one pass
__global__ void k_hist16(const int* __restrict__ batch, const float* __restrict__ scores,
                         int n, u32* __restrict__ hist, WsHdr* ws) {
  __shared__ int h[NBATCH];
  if (threadIdx.x < NBATCH) h[threadIdx.x] = 0;
  __syncthreads();
  int stride = gridDim.x * blockDim.x;
  for (int i = blockIdx.x * blockDim.x + threadIdx.x; i < n; i += stride) {
    int b = batch[i];
    u32 t = ordbits(scores[i]) >> 16;
    atomicAdd(&hist[(size_t)b * NBIN16 + t], 1u);
    atomicAdd(&h[b], 1);
  }
  __syncthreads();
  if (threadIdx.x < NBATCH) atomicAdd(&ws->counts[threadIdx.x], h[threadIdx.x]);
}

__global__ void k_scan(WsHdr* ws) {
  if (threadIdx.x == 0) {
    int acc = 0;
    for (int b = 0; b < NBATCH; ++b) {
      int c = ws->counts[b];
      ws->starts[b] = acc;
      ws->ndrop[b] = c >> 1;   // floor(c * 0.5) exact
      acc += c;
    }
  }
}

// two-level parallel select of the bucket containing the k-th smallest key
__global__ void k_pick16(const u32* __restrict__ hist, WsHdr* ws) {
  __shared__ int sc[256];
  __shared__ int sh_w, sh_krem;
  int b = blockIdx.x, t = threadIdx.x;
  const u32* h = hist + (size_t)b * NBIN16;
  if (ws->counts[b] == 0) {
    if (t == 0) { ws->sel16[b] = 0x10000; ws->krem2[b] = 0; }
    return;
  }
  int krem = ws->ndrop[b];
  // level 1: stripe sums (stripe t = bins [t*256, t*256+256))
  int s = 0;
  for (int j = 0; j < 256; ++j) s += h[t * 256 + j];
  sc[t] = s; __syncthreads();
  for (int off = 1; off < 256; off <<= 1) {          // Hillis-Steele inclusive scan
    int v = (t >= off) ? sc[t - off] : 0;
    __syncthreads(); sc[t] += v; __syncthreads();
  }
  int excl = sc[t] - s;
  if (krem >= excl && krem < excl + s) { sh_w = t; sh_krem = krem - excl; }
  __syncthreads();
  int W = sh_w, krem1 = sh_krem;
  // level 2: the 256 bins of winning stripe, coalesced single read each
  int c = (int)h[W * 256 + t];
  sc[t] = c; __syncthreads();
  for (int off = 1; off < 256; off <<= 1) {
    int v = (t >= off) ? sc[t - off] : 0;
    __syncthreads(); sc[t] += v; __syncthreads();
  }
  int excl2 = sc[t] - c;
  if (krem1 >= excl2 && krem1 < excl2 + c) {
    ws->sel16[b] = W * 256 + t;
    ws->krem2[b] = krem1 - excl2;
  }
}

__global__ void k_compact(const int* __restrict__ batch, const float* __restrict__ scores,
                          int n, WsHdr* ws, u64* __restrict__ cand) {
  int stride = gridDim.x * blockDim.x;
  for (int i = blockIdx.x * blockDim.x + threadIdx.x; i < n; i += stride) {
    int b = batch[i];
    u32 ob = ordbits(scores[i]);
    if ((int)(ob >> 16) == ws->sel16[b]) {
      int p = atomicAdd(&ws->ccount[b], 1);
      if (p < CAP)
        cand[(size_t)b * CAP + p] = ((u64)ob << 24) | (u32)(i - ws->starts[b]);
    }
  }
}

__global__ void k_final(WsHdr* ws, const u64* __restrict__ cand) {
  __shared__ u64 ck[CAP];
  int b = blockIdx.x, t = threadIdx.x;
  int m = ws->ccount[b]; if (m > CAP) m = CAP;
  if (m == 0) { if (t == 0) ws->keysel[b] = 0ull; return; }
  for (int j = t; j < m; j += 256) ck[j] = cand[(size_t)b * CAP + j];
  __syncthreads();
  int krem = ws->krem2[b];
  for (int j = t; j < m; j += 256) {
    u64 key = ck[j];
    int r = 0;
    for (int q = 0; q < m; ++q) r += (ck[q] < key);  // broadcast LDS reads
    if (r == krem) ws->keysel[b] = key;
  }
}

// ---------------- fallback path (small ws): round-1 passing kernels ----------------

__global__ void k_zero(WsHdr* ws) {
  int t = threadIdx.x;
  if (t < NBATCH) ws->counts[t] = 0;
}

__global__ void k_hist(const int* __restrict__ batch, int n, WsHdr* ws) {
  __shared__ int h[NBATCH];
  if (threadIdx.x < NBATCH) h[threadIdx.x] = 0;
  __syncthreads();
  int stride = gridDim.x * blockDim.x;
  for (int i = blockIdx.x * blockDim.x + threadIdx.x; i < n; i += stride)
    atomicAdd(&h[batch[i]], 1);
  __syncthreads();
  if (threadIdx.x < NBATCH) atomicAdd(&ws->counts[threadIdx.x], h[threadIdx.x]);
}

__global__ void k_select(const float* __restrict__ scores, WsHdr* ws) {
  __shared__ u32 hist[256];
  __shared__ u64 sh_prefix;
  __shared__ int sh_krem;
  int b = blockIdx.x;
  int start = ws->starts[b];
  int cnt = ws->counts[b];
  if (threadIdx.x == 0) { sh_prefix = 0ull; sh_krem = ws->ndrop[b]; }
  __syncthreads();
  for (int shift = 48; shift >= 0; shift -= 8) {
    for (int j = threadIdx.x; j < 256; j += blockDim.x) hist[j] = 0;
    __syncthreads();
    u64 prefix = sh_prefix;
    for (int idx = threadIdx.x; idx < cnt; idx += blockDim.x) {
      u64 key = ((u64)ordbits(scores[start + idx]) << 24) | (u32)idx;
      if ((key >> (shift + 8)) == prefix)
        atomicAdd(&hist[(u32)(key >> shift) & 255u], 1u);
    }
    __syncthreads();
    if (threadIdx.x == 0) {
      int krem = sh_krem;
      u32 cum = 0, sel = 255;
      for (int j = 0; j < 256; ++j) {
        u32 c = hist[j];
        if ((u32)krem < cum + c) { sel = (u32)j; krem -= (int)cum; break; }
        cum += c;
      }
      sh_prefix = (prefix << 8) | sel;
      sh_krem = krem;
    }
    __syncthreads();
  }
  if (threadIdx.x == 0) ws->keysel[b] = sh_prefix;
}

// ---------------- apply (shared by both paths) ----------------

__global__ void k_apply(const float4* __restrict__ feats4,
                        const int* __restrict__ batch,
                        const float* __restrict__ scores,
                        const WsHdr* __restrict__ ws,
                        float4* __restrict__ out4, int n) {
  __shared__ float m[16];
  int t = threadIdx.x;
  int pl = t >> 4, ch = t & 15;
  int i = blockIdx.x * 16 + pl;
  if (ch == 0) {
    float keep = 0.f;
    if (i < n) {
      int b = batch[i];
      int start = ws->starts[b];
      u64 key = ((u64)ordbits(scores[i]) << 24) | (u32)(i - start);
      keep = (key >= ws->keysel[b]) ? 1.f : 0.f;
    }
    m[pl] = keep;
  }
  __syncthreads();
  if (i < n) {
    size_t off = (size_t)i * 16 + (size_t)ch;
    float4 v = feats4[off];
    float s = m[pl];
    v.x *= s; v.y *= s; v.z *= s; v.w *= s;
    out4[off] = v;
  }
}

extern "C" void kernel_launch(void* const* d_in, const int* in_sizes, int n_in,
                              void* d_out, int out_size, void* d_ws, size_t ws_size,
                              hipStream_t stream) {
  const float* feats  = (const float*)d_in[0];
  const int*   batch  = (const int*)d_in[1];
  const float* scores = (const float*)d_in[2];
  float* out = (float*)d_out;
  int n = in_sizes[1];
  WsHdr* ws = (WsHdr*)d_ws;

  const size_t hist_bytes = (size_t)NBATCH * NBIN16 * sizeof(u32);   // 8 MB
  const size_t cand_bytes = (size_t)NBATCH * CAP * sizeof(u64);      // 1 MB
  const size_t need = sizeof(WsHdr) + hist_bytes + cand_bytes;

  if (ws_size >= need) {
    u32* hist = (u32*)((char*)d_ws + sizeof(WsHdr));
    u64* cand = (u64*)((char*)d_ws + sizeof(WsHdr) + hist_bytes);
    int n16 = (int)((sizeof(WsHdr) + hist_bytes) / 16);  // both 16B multiples
    k_zero_all<<<2048, 256, 0, stream>>>((float4*)d_ws, n16);
    k_hist16 <<<2048, 256, 0, stream>>>(batch, scores, n, hist, ws);
    k_scan   <<<1, 64, 0, stream>>>(ws);
    k_pick16 <<<NBATCH, 256, 0, stream>>>(hist, ws);
    k_compact<<<2048, 256, 0, stream>>>(batch, scores, n, ws, cand);
    k_final  <<<NBATCH, 256, 0, stream>>>(ws, cand);
  } else {
    k_zero  <<<1, 64, 0, stream>>>(ws);
    k_hist  <<<1024, 256, 0, stream>>>(batch, n, ws);
    k_scan  <<<1, 64, 0, stream>>>(ws);
    k_select<<<NBATCH, 256, 0, stream>>>(scores, ws);
  }

  int blocks = (n + 15) / 16;   // 16 rows per block, 16 float4 per row
  k_apply<<<blocks, 256, 0, stream>>>((const float4*)feats, batch, scores, ws,
                                      (float4*)out, n);
}